// Round 8
// baseline (545.683 us; speedup 1.0000x reference)
//
#include <hip/hip_runtime.h>
#include <hip/hip_bf16.h>
#include <stdint.h>

#define IN_DIM    256
#define OUT_DIM   256
#define NUM_HEADS 4
#define HEAD_DIM  64
#define N_SRC     100000
#define N_DST     50000
#define N_EDGES   300000

#define SCAN_NBLK ((N_DST + 1023) / 1024)      // 49
#define WCVT_BLKS 96

typedef __attribute__((ext_vector_type(8))) short v8s;   // 8 x bf16 bits
typedef __attribute__((ext_vector_type(4))) float v4f;   // MFMA accumulator

__device__ __forceinline__ unsigned short f2bf(float f) {
    unsigned u = __float_as_uint(f);
    unsigned r = (u + 0x7FFFu + ((u >> 16) & 1u)) >> 16;   // RNE
    return (unsigned short)r;
}
__device__ __forceinline__ float bf2f(unsigned short s) {
    return __uint_as_float(((unsigned)s) << 16);
}

// -------------------- weights fp32 -> bf16  (+ cnt zeroing, folded memset)
__global__ void wcvt_kernel(const float* __restrict__ wq,
                            const float* __restrict__ wk,
                            const float* __restrict__ wv,
                            unsigned short* __restrict__ dst,
                            int* __restrict__ cnt) {
    if (blockIdx.x >= WCVT_BLKS) {
        // zero cnt[50000] with int4 stores (N_DST % 4 == 0)
        int i = (blockIdx.x - WCVT_BLKS) * 1024 + threadIdx.x * 4;
        if (i < N_DST) *(int4*)(cnt + i) = make_int4(0, 0, 0, 0);
        return;
    }
    int i = blockIdx.x * 256 + threadIdx.x;
    if (i >= 3 * 8192) return;
    int m = i >> 13;                  // which matrix
    int r = i & 8191;                 // v8 group within matrix
    const float* s = (m == 0) ? wq : (m == 1) ? wk : wv;
    const float4* sp = (const float4*)(s + (size_t)r * 8);
    float4 x = sp[0], y = sp[1];
    v8s o;
    o[0] = (short)f2bf(x.x); o[1] = (short)f2bf(x.y);
    o[2] = (short)f2bf(x.z); o[3] = (short)f2bf(x.w);
    o[4] = (short)f2bf(y.x); o[5] = (short)f2bf(y.y);
    o[6] = (short)f2bf(y.z); o[7] = (short)f2bf(y.w);
    *(v8s*)(dst + (size_t)m * 65536 + (size_t)r * 8) = o;
}

// ------------------- barrier-free register GEMM: Out = bf16(A_f32) @ W^T + b
// r8: NO LDS, NO barriers in the k-loop. Each wave owns a 64x32 panel fully
// in registers: A fp32 direct-to-reg (dbuf-2, cvt in loop), B bf16
// direct-to-reg (W is L2-resident, 384KB). 4 waves/block share the 64-row
// A panel (L1/L2 reuse). ILP (10 loads in flight) + free-running TLP hide
// latency; no lockstep. LDS (16KB) only for the coalesced store bounce.
__global__ __launch_bounds__(256, 3) void gemm_kernel(
    const float* __restrict__ h_src, const float* __restrict__ h_dst,
    const unsigned short* __restrict__ Wb,
    const float* __restrict__ bq, const float* __restrict__ bk,
    const float* __restrict__ bv,
    unsigned short* __restrict__ Q, unsigned short* __restrict__ K,
    unsigned short* __restrict__ V) {

    __shared__ unsigned short smem[64 * 128];  // 16KB epilogue bounce

    int z = blockIdx.z;
    const float* A; const unsigned short* W;
    const float* bias; unsigned short* Out; int M;
    if (z == 0)      { A = h_dst; W = Wb;          bias = bq; Out = Q; M = N_DST; }
    else if (z == 1) { A = h_src; W = Wb + 65536;  bias = bk; Out = K; M = N_SRC; }
    else             { A = h_src; W = Wb + 131072; bias = bv; Out = V; M = N_SRC; }

    int pbase = blockIdx.x * 64;               // 64-row panel
    if (pbase >= M) return;                    // z==0 tail blocks (uniform)
    int nbase = blockIdx.y * 128;              // 128-col half

    int tid = threadIdx.x;
    int wv = tid >> 6, lane = tid & 63;
    int lm = lane & 15, quad = lane >> 4;

    // A-fragment row pointers (clamped; stores guarded later).
    // Lane layout per MFMA A-frag: row = lm, k = quad*8 + e.
    const float* pA[4];
#pragma unroll
    for (int i = 0; i < 4; i++) {
        int gr = pbase + i * 16 + lm;
        if (gr > M - 1) gr = M - 1;
        pA[i] = A + (size_t)gr * 256 + quad * 8;
    }
    // B-fragment pointers: col = nbase + wv*32 + j*16 + lm, k = quad*8 + e.
    const unsigned short* pB[2];
#pragma unroll
    for (int j = 0; j < 2; j++)
        pB[j] = W + (size_t)(nbase + wv * 32 + j * 16 + lm) * 256 + quad * 8;

    v4f acc[4][2];
#pragma unroll
    for (int i = 0; i < 4; i++)
#pragma unroll
        for (int j = 0; j < 2; j++) acc[i][j] = (v4f){0, 0, 0, 0};

    // register double-buffers (all indices compile-time after full unroll)
    float4 abuf[2][4][2];                      // [buf][i][lo/hi]
    v8s    bbuf[2][2];                         // [buf][j]

    // prologue: k-step 0 into buf 0
#pragma unroll
    for (int i = 0; i < 4; i++) {
        abuf[0][i][0] = *(const float4*)(pA[i]);
        abuf[0][i][1] = *(const float4*)(pA[i] + 4);
    }
#pragma unroll
    for (int j = 0; j < 2; j++) bbuf[0][j] = *(const v8s*)(pB[j]);

#pragma unroll
    for (int ks = 0; ks < 8; ks++) {
        int cur = ks & 1, nxt = cur ^ 1;
        if (ks + 1 < 8) {
            // issue next k-step's loads first; they fly under cvt+MFMA
#pragma unroll
            for (int i = 0; i < 4; i++) {
                abuf[nxt][i][0] = *(const float4*)(pA[i] + (ks + 1) * 32);
                abuf[nxt][i][1] = *(const float4*)(pA[i] + (ks + 1) * 32 + 4);
            }
#pragma unroll
            for (int j = 0; j < 2; j++)
                bbuf[nxt][j] = *(const v8s*)(pB[j] + (ks + 1) * 32);
        }
        // cvt current A (compiler waits only on buf[cur] loads)
        v8s af[4];
#pragma unroll
        for (int i = 0; i < 4; i++) {
            float4 lo = abuf[cur][i][0], hi = abuf[cur][i][1];
            v8s o;
            o[0] = (short)f2bf(lo.x); o[1] = (short)f2bf(lo.y);
            o[2] = (short)f2bf(lo.z); o[3] = (short)f2bf(lo.w);
            o[4] = (short)f2bf(hi.x); o[5] = (short)f2bf(hi.y);
            o[6] = (short)f2bf(hi.z); o[7] = (short)f2bf(hi.w);
            af[i] = o;
        }
#pragma unroll
        for (int i = 0; i < 4; i++)
#pragma unroll
            for (int j = 0; j < 2; j++)
                acc[i][j] = __builtin_amdgcn_mfma_f32_16x16x32_bf16(
                    af[i], bbuf[cur][j], acc[i][j], 0, 0, 0);
    }

    // ---- epilogue: bias + cvt -> LDS bounce -> coalesced 16B row stores
    // C/D frag: col = lm, row = quad*4 + r
#pragma unroll
    for (int j = 0; j < 2; j++) {
        int col = wv * 32 + j * 16 + lm;
        float bcol = bias[nbase + col];
#pragma unroll
        for (int i = 0; i < 4; i++)
#pragma unroll
            for (int r = 0; r < 4; r++)
                smem[(i * 16 + quad * 4 + r) * 128 + col] =
                    f2bf(acc[i][j][r] + bcol);
    }
    __syncthreads();
    // 64 rows x 128 cols bf16 = 1024 16B-chunks; 256 threads x 4
#pragma unroll
    for (int k = 0; k < 4; k++) {
        int c = tid + k * 256;
        int rl = c >> 4, ch = c & 15;
        int grow = pbase + rl;
        if (grow < M)
            *(v8s*)(Out + (size_t)grow * 256 + nbase + ch * 8) =
                *(const v8s*)&smem[rl * 128 + ch * 8];
    }
}

// ----------------------------------------------------------- CSR building
__global__ void hist_kernel(const int* __restrict__ dst_idx,
                            int* __restrict__ cnt) {
    int i = blockIdx.x * 256 + threadIdx.x;
    if (i < N_EDGES) atomicAdd(&cnt[dst_idx[i]], 1);
}

// Hierarchical scan, phase 1: block-local exclusive prefix (coalesced,
// shfl-based wave scan) + per-block sums. Writes offsets AND cursor with
// the block-LOCAL value; consumers add bsum[d>>10] (fixup kernel removed).
__global__ __launch_bounds__(1024) void scan_local_kernel(
    const int* __restrict__ cnt, int* __restrict__ offsets,
    int* __restrict__ cursor, int* __restrict__ bsum) {
    __shared__ int wsum[16];
    int t = threadIdx.x, b = blockIdx.x;
    int i = b * 1024 + t;
    int lane = t & 63, w = t >> 6;
    int v = (i < N_DST) ? cnt[i] : 0;
    int s = v;                                  // inclusive wave scan
#pragma unroll
    for (int off = 1; off < 64; off <<= 1) {
        int u = __shfl_up(s, off, 64);
        if (lane >= off) s += u;
    }
    if (lane == 63) wsum[w] = s;
    __syncthreads();
    if (w == 0) {
        int x = (lane < 16) ? wsum[lane] : 0;   // scan the 16 wave sums
#pragma unroll
        for (int off = 1; off < 16; off <<= 1) {
            int u = __shfl_up(x, off, 64);
            if (lane >= off) x += u;
        }
        if (lane < 16) wsum[lane] = x;          // inclusive
    }
    __syncthreads();
    int wbase = (w == 0) ? 0 : wsum[w - 1];
    if (i < N_DST) {
        int e = wbase + s - v;                  // block-local exclusive
        offsets[i] = e;
        cursor[i] = e;
    }
    if (t == 1023) bsum[b] = wsum[15];          // block total
}

// Phase 2: one wave scans the 49 block sums in-place -> exclusive bases.
__global__ void scan_base_kernel(int* __restrict__ bsum) {
    int lane = threadIdx.x;                     // 64 threads
    int v = (lane < SCAN_NBLK) ? bsum[lane] : 0;
    int s = v;
#pragma unroll
    for (int off = 1; off < 64; off <<= 1) {
        int u = __shfl_up(s, off, 64);
        if (lane >= off) s += u;
    }
    if (lane < SCAN_NBLK) bsum[lane] = s - v;   // exclusive base
}

__global__ void scatter_kernel(const int* __restrict__ src_idx,
                               const int* __restrict__ dst_idx,
                               int* __restrict__ cursor,
                               const int* __restrict__ bsum,
                               int* __restrict__ esrc) {
    int i = blockIdx.x * 256 + threadIdx.x;
    if (i >= N_EDGES) return;
    int d = dst_idx[i];
    int pos = atomicAdd(&cursor[d], 1) + bsum[d >> 10];
    esrc[pos] = src_idx[i];
}

// -------------- fused score + online-softmax + aggregation (one wave/dst)
__global__ __launch_bounds__(256) void agg_kernel(
    const int* __restrict__ esrc, const int* __restrict__ offsets,
    const int* __restrict__ bsum,
    const unsigned short* __restrict__ Q, const unsigned short* __restrict__ K,
    const unsigned short* __restrict__ V, float* __restrict__ out) {

    int wave = threadIdx.x >> 6, lane = threadIdx.x & 63;
    int d = blockIdx.x * 4 + wave;
    if (d >= N_DST) return;

    int start = offsets[d] + bsum[d >> 10];
    int end = (d + 1 == N_DST) ? N_EDGES
                               : offsets[d + 1] + bsum[(d + 1) >> 10];
    float4 o = make_float4(0.f, 0.f, 0.f, 0.f);

    if (end > start) {
        ushort4 qv = *((const ushort4*)(Q + (size_t)d * 256) + lane);
        float q0 = bf2f(qv.x), q1 = bf2f(qv.y), q2 = bf2f(qv.z), q3 = bf2f(qv.w);

        float m = -3.0e38f, l = 0.f;
        float a0 = 0.f, a1 = 0.f, a2 = 0.f, a3 = 0.f;

        int s0 = esrc[start];
        int sN = (start + 1 < end) ? esrc[start + 1] : 0;
        ushort4 kv = *((const ushort4*)(K + (size_t)s0 * 256) + lane);
        ushort4 vv = *((const ushort4*)(V + (size_t)s0 * 256) + lane);

        for (int j = start; j < end; j++) {
            ushort4 kc = kv, vc = vv;
            int sNN = (j + 2 < end) ? esrc[j + 2] : 0;
            if (j + 1 < end) {
                kv = *((const ushort4*)(K + (size_t)sN * 256) + lane);
                vv = *((const ushort4*)(V + (size_t)sN * 256) + lane);
            }
            sN = sNN;

            float p = bf2f(kc.x) * q0 + bf2f(kc.y) * q1 +
                      bf2f(kc.z) * q2 + bf2f(kc.w) * q3;
            p += __shfl_xor(p, 1, 64);
            p += __shfl_xor(p, 2, 64);
            p += __shfl_xor(p, 4, 64);
            p += __shfl_xor(p, 8, 64);
            p *= 0.125f;                           // 1/sqrt(64)

            float mn = fmaxf(m, p);
            float sc = __expf(m - mn);             // first iter: exp(-huge)=0
            float w  = __expf(p - mn);
            l = l * sc + w;
            a0 = a0 * sc + w * bf2f(vc.x);
            a1 = a1 * sc + w * bf2f(vc.y);
            a2 = a2 * sc + w * bf2f(vc.z);
            a3 = a3 * sc + w * bf2f(vc.w);
            m = mn;
        }
        float inv = 1.0f / l;
        o = make_float4(a0 * inv, a1 * inv, a2 * inv, a3 * inv);
    }
    *((float4*)(out + (size_t)d * 256) + lane) = o;   // empty dst -> zeros
}

// --------------------------------------------------------------- launcher
extern "C" void kernel_launch(void* const* d_in, const int* in_sizes, int n_in,
                              void* d_out, int out_size, void* d_ws, size_t ws_size,
                              hipStream_t stream) {
    const float* h_src   = (const float*)d_in[0];
    const float* h_dst   = (const float*)d_in[1];
    const int*   src_idx = (const int*)d_in[2];
    const int*   dst_idx = (const int*)d_in[3];
    const float* Wq      = (const float*)d_in[4];
    const float* bq      = (const float*)d_in[5];
    const float* Wk      = (const float*)d_in[6];
    const float* bk      = (const float*)d_in[7];
    const float* Wv      = (const float*)d_in[8];
    const float* bv      = (const float*)d_in[9];
    float* out = (float*)d_out;

    char* ws = (char*)d_ws;
    size_t off = 0;
    auto take = [&](size_t bytes) { char* p = ws + off; off = (off + bytes + 255) & ~(size_t)255; return p; };
    unsigned short* Q       = (unsigned short*)take((size_t)N_DST * 256 * 2);
    unsigned short* K       = (unsigned short*)take((size_t)N_SRC * 256 * 2);
    unsigned short* V       = (unsigned short*)take((size_t)N_SRC * 256 * 2);
    unsigned short* Wb      = (unsigned short*)take((size_t)3 * 65536 * 2);
    int*            cnt     = (int*)take((size_t)N_DST * 4);
    int*            offsets = (int*)take((size_t)(N_DST + 1) * 4);
    int*            cursor  = (int*)take((size_t)N_DST * 4);
    int*            esrc    = (int*)take((size_t)N_EDGES * 4);
    int*            bsum    = (int*)take((size_t)64 * 4);
    (void)ws_size; (void)in_sizes; (void)n_in; (void)out_size;

    // weights cvt + cnt zeroing (folded memset): 96 + 49 blocks
    wcvt_kernel<<<WCVT_BLKS + SCAN_NBLK, 256, 0, stream>>>(Wq, Wk, Wv, Wb, cnt);

    // CSR build: hist -> scan (2 launches, fixup folded into consumers)
    hist_kernel<<<(N_EDGES + 255) / 256, 256, 0, stream>>>(dst_idx, cnt);
    scan_local_kernel<<<SCAN_NBLK, 1024, 0, stream>>>(cnt, offsets, cursor, bsum);
    scan_base_kernel<<<1, 64, 0, stream>>>(bsum);
    scatter_kernel<<<(N_EDGES + 255) / 256, 256, 0, stream>>>(src_idx, dst_idx,
                                                              cursor, bsum, esrc);

    // barrier-free register GEMM: 64-row panels x 128-col halves x {Q,K,V}
    gemm_kernel<<<dim3((N_SRC + 63) / 64, 2, 3), 256, 0, stream>>>(
        h_src, h_dst, Wb, bq, bk, bv, Q, K, V);

    agg_kernel<<<(N_DST + 3) / 4, 256, 0, stream>>>(esrc, offsets, bsum, Q, K, V, out);
}

// Round 9
// 344.076 us; speedup vs baseline: 1.5859x; 1.5859x over previous
//
#include <hip/hip_runtime.h>
#include <hip/hip_bf16.h>
#include <stdint.h>

#define IN_DIM    256
#define OUT_DIM   256
#define NUM_HEADS 4
#define HEAD_DIM  64
#define N_SRC     100000
#define N_DST     50000
#define N_EDGES   300000

#define BM 128
#define BN 256
#define BK 32
#define SCAN_NBLK ((N_DST + 1023) / 1024)      // 49
#define WCVT_BLKS 96

typedef __attribute__((ext_vector_type(8))) short v8s;   // 8 x bf16 bits
typedef __attribute__((ext_vector_type(4))) float v4f;   // MFMA accumulator

__device__ __forceinline__ unsigned short f2bf(float f) {
    unsigned u = __float_as_uint(f);
    unsigned r = (u + 0x7FFFu + ((u >> 16) & 1u)) >> 16;   // RNE
    return (unsigned short)r;
}
__device__ __forceinline__ float bf2f(unsigned short s) {
    return __uint_as_float(((unsigned)s) << 16);
}

// async global->LDS, 16B per lane; lds base is wave-uniform, lane i deposits
// at base + i*16 (guide §5: width=16 variant, global_load_lds_dwordx4)
__device__ __forceinline__ void async_copy16(const unsigned short* g,
                                             unsigned short* l) {
    __builtin_amdgcn_global_load_lds(
        (const __attribute__((address_space(1))) unsigned int*)g,
        (__attribute__((address_space(3))) unsigned int*)l, 16, 0, 0);
}

// -------------------- weights fp32 -> bf16  (+ cnt zeroing, folded memset)
__global__ void wcvt_kernel(const float* __restrict__ wq,
                            const float* __restrict__ wk,
                            const float* __restrict__ wv,
                            unsigned short* __restrict__ dst,
                            int* __restrict__ cnt) {
    if (blockIdx.x >= WCVT_BLKS) {
        // zero cnt[50000] with int4 stores (N_DST % 4 == 0)
        int i = (blockIdx.x - WCVT_BLKS) * 1024 + threadIdx.x * 4;
        if (i < N_DST) *(int4*)(cnt + i) = make_int4(0, 0, 0, 0);
        return;
    }
    int i = blockIdx.x * 256 + threadIdx.x;
    if (i >= 3 * 8192) return;
    int m = i >> 13;                  // which matrix
    int r = i & 8191;                 // v8 group within matrix
    const float* s = (m == 0) ? wq : (m == 1) ? wk : wv;
    const float4* sp = (const float4*)(s + (size_t)r * 8);
    float4 x = sp[0], y = sp[1];
    v8s o;
    o[0] = (short)f2bf(x.x); o[1] = (short)f2bf(x.y);
    o[2] = (short)f2bf(x.z); o[3] = (short)f2bf(x.w);
    o[4] = (short)f2bf(y.x); o[5] = (short)f2bf(y.y);
    o[6] = (short)f2bf(y.z); o[7] = (short)f2bf(y.w);
    *(v8s*)(dst + (size_t)m * 65536 + (size_t)r * 8) = o;
}

// ------------------- fused-cvt tiled GEMM: Out = bf16(A_f32) @ W^T + b
// r9: RESTORED r5 structure (measured 103.8 us): 512 thr / 8 waves, 128x256
// tile, dbuf-2 B via global_load_lds, distance-2 A register prefetch,
// counted vmcnt(2) drains, LDS-bounce coalesced epilogue.
__global__ __launch_bounds__(512, 2) void gemm_kernel(
    const float* __restrict__ h_src, const float* __restrict__ h_dst,
    const unsigned short* __restrict__ Wb,
    const float* __restrict__ bq, const float* __restrict__ bk,
    const float* __restrict__ bv,
    unsigned short* __restrict__ Q, unsigned short* __restrict__ K,
    unsigned short* __restrict__ V) {

    // 48 KB: sA[2][128][32] = smem[0..8191] | sB[2][256][32] = smem[8192..]
    // epilogue reuses smem[0..16383] as [64][256] bf16 bounce buffer
    __shared__ unsigned short smem[24576];

    int z = blockIdx.z;
    const float* A; const unsigned short* W;
    const float* bias; unsigned short* Out; int M;
    if (z == 0)      { A = h_dst; W = Wb;          bias = bq; Out = Q; M = N_DST; }
    else if (z == 1) { A = h_src; W = Wb + 65536;  bias = bk; Out = K; M = N_SRC; }
    else             { A = h_src; W = Wb + 131072; bias = bv; Out = V; M = N_SRC; }

    int mbase = blockIdx.x * BM;
    if (mbase >= M) return;                    // z==0 tail blocks (uniform)

    int tid  = threadIdx.x;
    int wave = tid >> 6, lane = tid & 63;
    int lm = lane & 15, quad = lane >> 4;
    int wrow = wave >> 2;                      // 0..1 -> 64-row band
    int wcol = wave & 3;                       // 0..3 -> 64-col band

    // A staging coords: thread t -> row t/4, col chunk (t&3)*8 (fp32)
    int ar = tid >> 2, akc = (tid & 3) * 8;
    int gr = mbase + ar; if (gr > M - 1) gr = M - 1;   // clamp; stores guarded
    const float* gA = A + (size_t)gr * 256 + akc;

    // B staging coords: wave w covers rows w*32..w*32+31 (two async issues)
    int sr = lane >> 2, skc = (lane & 3) * 8;
    const unsigned short* gB0 = W + (size_t)(wave * 32 + sr) * 256 + skc;
    const unsigned short* gB1 = gB0 + (size_t)16 * 256;

    v4f acc[4][4];
#pragma unroll
    for (int i = 0; i < 4; i++)
#pragma unroll
        for (int j = 0; j < 4; j++) acc[i][j] = (v4f){0, 0, 0, 0};

    const int NK = 256 / BK;                   // 8

    // ---- prologue: A(0) reg->cvt->LDS, B(0) async, A(1) issued in-flight
    float4 xc, yc;
    {
        float4 x0 = *(const float4*)(gA);
        float4 y0 = *(const float4*)(gA + 4);
        async_copy16(gB0, &smem[8192 + (wave * 32) * 32]);
        async_copy16(gB1, &smem[8192 + (wave * 32 + 16) * 32]);
        xc = *(const float4*)(gA + BK);        // A(1), stays in flight
        yc = *(const float4*)(gA + BK + 4);
        v8s o;
        o[0] = (short)f2bf(x0.x); o[1] = (short)f2bf(x0.y);
        o[2] = (short)f2bf(x0.z); o[3] = (short)f2bf(x0.w);
        o[4] = (short)f2bf(y0.x); o[5] = (short)f2bf(y0.y);
        o[6] = (short)f2bf(y0.z); o[7] = (short)f2bf(y0.w);
        *(v8s*)&smem[(size_t)ar * 32 + akc] = o;
        // drain B(0) copies + ds_write; keep A(1) loads in flight
        asm volatile("s_waitcnt vmcnt(2) lgkmcnt(0)" ::: "memory");
        __builtin_amdgcn_s_barrier();
        __builtin_amdgcn_sched_barrier(0);
    }

    int buf = 0;
#pragma unroll
    for (int ks = 0; ks < NK; ks++) {
        float4 xn, yn;
        if (ks + 1 < NK) {
            // issue next B async copies into buf^1
            int k0 = (ks + 1) * BK;
            async_copy16(gB0 + k0,
                         &smem[8192 + (buf ^ 1) * 8192 + (wave * 32) * 32]);
            async_copy16(gB1 + k0,
                         &smem[8192 + (buf ^ 1) * 8192 + (wave * 32 + 16) * 32]);
        }
        if (ks + 2 < NK) {
            // distance-2 A prefetch (registers; survives the barrier)
            int k0 = (ks + 2) * BK;
            xn = *(const float4*)(gA + k0);
            yn = *(const float4*)(gA + k0 + 4);
        }

        const unsigned short* sAb = smem + buf * 4096;
        const unsigned short* sBb = smem + 8192 + buf * 8192;
        v8s af[4], bfr[4];
#pragma unroll
        for (int i = 0; i < 4; i++)
            af[i] = *(const v8s*)&sAb[(wrow * 64 + i * 16 + lm) * 32 + quad * 8];
#pragma unroll
        for (int j = 0; j < 4; j++)
            bfr[j] = *(const v8s*)&sBb[(wcol * 64 + j * 16 + lm) * 32 + quad * 8];
#pragma unroll
        for (int i = 0; i < 4; i++)
#pragma unroll
            for (int j = 0; j < 4; j++)
                acc[i][j] = __builtin_amdgcn_mfma_f32_16x16x32_bf16(
                    af[i], bfr[j], acc[i][j], 0, 0, 0);

        if (ks + 1 < NK) {
            // cvt A(ks+1) (compiler inserts vmcnt(4): retires xc/yc only)
            v8s o;
            o[0] = (short)f2bf(xc.x); o[1] = (short)f2bf(xc.y);
            o[2] = (short)f2bf(xc.z); o[3] = (short)f2bf(xc.w);
            o[4] = (short)f2bf(yc.x); o[5] = (short)f2bf(yc.y);
            o[6] = (short)f2bf(yc.z); o[7] = (short)f2bf(yc.w);
            *(v8s*)&smem[(buf ^ 1) * 4096 + (size_t)ar * 32 + akc] = o;
            // barrier: retire B(ks+1) copies (+ds_write); A(ks+2) in flight
            if (ks + 2 < NK)
                asm volatile("s_waitcnt vmcnt(2) lgkmcnt(0)" ::: "memory");
            else
                asm volatile("s_waitcnt vmcnt(0) lgkmcnt(0)" ::: "memory");
            __builtin_amdgcn_s_barrier();
            __builtin_amdgcn_sched_barrier(0);
        }
        xc = xn; yc = yn;
        buf ^= 1;
    }

    // ---- epilogue: LDS bounce -> full-row coalesced stores
    // 64 rows x 256 cols bf16 = 32KB per pass, 2 passes (wrow 0 then 1)
#pragma unroll
    for (int p = 0; p < 2; p++) {
        __syncthreads();                       // smem free for this pass
        if (wrow == p) {
#pragma unroll
            for (int j = 0; j < 4; j++) {
                int col = wcol * 64 + j * 16 + lm;
                float bcol = bias[col];
#pragma unroll
                for (int i = 0; i < 4; i++)
#pragma unroll
                    for (int r = 0; r < 4; r++)
                        smem[(i * 16 + quad * 4 + r) * 256 + col] =
                            f2bf(acc[i][j][r] + bcol);
            }
        }
        __syncthreads();
#pragma unroll
        for (int k = 0; k < 4; k++) {
            int c = tid + k * 512;             // 0..2047 16B-chunks
            int rl = c >> 5, ch = c & 31;
            int grow = mbase + p * 64 + rl;
            if (grow < M)
                *(v8s*)(Out + (size_t)grow * 256 + ch * 8) =
                    *(const v8s*)&smem[rl * 256 + ch * 8];
        }
    }
}

// ----------------------------------------------------------- CSR building
__global__ void hist_kernel(const int* __restrict__ dst_idx,
                            int* __restrict__ cnt) {
    int i = blockIdx.x * 256 + threadIdx.x;
    if (i < N_EDGES) atomicAdd(&cnt[dst_idx[i]], 1);
}

// Hierarchical scan, phase 1: block-local exclusive prefix (coalesced,
// shfl-based wave scan) + per-block sums. Writes offsets AND cursor with
// the block-LOCAL value; consumers add bsum[d>>10] (fixup kernel removed).
__global__ __launch_bounds__(1024) void scan_local_kernel(
    const int* __restrict__ cnt, int* __restrict__ offsets,
    int* __restrict__ cursor, int* __restrict__ bsum) {
    __shared__ int wsum[16];
    int t = threadIdx.x, b = blockIdx.x;
    int i = b * 1024 + t;
    int lane = t & 63, w = t >> 6;
    int v = (i < N_DST) ? cnt[i] : 0;
    int s = v;                                  // inclusive wave scan
#pragma unroll
    for (int off = 1; off < 64; off <<= 1) {
        int u = __shfl_up(s, off, 64);
        if (lane >= off) s += u;
    }
    if (lane == 63) wsum[w] = s;
    __syncthreads();
    if (w == 0) {
        int x = (lane < 16) ? wsum[lane] : 0;   // scan the 16 wave sums
#pragma unroll
        for (int off = 1; off < 16; off <<= 1) {
            int u = __shfl_up(x, off, 64);
            if (lane >= off) x += u;
        }
        if (lane < 16) wsum[lane] = x;          // inclusive
    }
    __syncthreads();
    int wbase = (w == 0) ? 0 : wsum[w - 1];
    if (i < N_DST) {
        int e = wbase + s - v;                  // block-local exclusive
        offsets[i] = e;
        cursor[i] = e;
    }
    if (t == 1023) bsum[b] = wsum[15];          // block total
}

// Phase 2: one wave scans the 49 block sums in-place -> exclusive bases.
__global__ void scan_base_kernel(int* __restrict__ bsum) {
    int lane = threadIdx.x;                     // 64 threads
    int v = (lane < SCAN_NBLK) ? bsum[lane] : 0;
    int s = v;
#pragma unroll
    for (int off = 1; off < 64; off <<= 1) {
        int u = __shfl_up(s, off, 64);
        if (lane >= off) s += u;
    }
    if (lane < SCAN_NBLK) bsum[lane] = s - v;   // exclusive base
}

__global__ void scatter_kernel(const int* __restrict__ src_idx,
                               const int* __restrict__ dst_idx,
                               int* __restrict__ cursor,
                               const int* __restrict__ bsum,
                               int* __restrict__ esrc) {
    int i = blockIdx.x * 256 + threadIdx.x;
    if (i >= N_EDGES) return;
    int d = dst_idx[i];
    int pos = atomicAdd(&cursor[d], 1) + bsum[d >> 10];
    esrc[pos] = src_idx[i];
}

// -------------- fused score + online-softmax + aggregation (one wave/dst)
// r9: depth-2 K/V row pipeline (rows j and j+1 resident, j+2 issued during
// j's compute; index fetched distance 3) -> 2 row-pairs in flight per wave.
__global__ __launch_bounds__(256) void agg_kernel(
    const int* __restrict__ esrc, const int* __restrict__ offsets,
    const int* __restrict__ bsum,
    const unsigned short* __restrict__ Q, const unsigned short* __restrict__ K,
    const unsigned short* __restrict__ V, float* __restrict__ out) {

    int wave = threadIdx.x >> 6, lane = threadIdx.x & 63;
    int d = blockIdx.x * 4 + wave;
    if (d >= N_DST) return;

    int start = offsets[d] + bsum[d >> 10];
    int end = (d + 1 == N_DST) ? N_EDGES
                               : offsets[d + 1] + bsum[(d + 1) >> 10];
    float4 o = make_float4(0.f, 0.f, 0.f, 0.f);

    if (end > start) {
        ushort4 qv = *((const ushort4*)(Q + (size_t)d * 256) + lane);
        float q0 = bf2f(qv.x), q1 = bf2f(qv.y), q2 = bf2f(qv.z), q3 = bf2f(qv.w);

        float m = -3.0e38f, l = 0.f;
        float a0 = 0.f, a1 = 0.f, a2 = 0.f, a3 = 0.f;

        int n = end - start;
        int i0 = esrc[start];
        int i1 = (n > 1) ? esrc[start + 1] : i0;
        int i2 = (n > 2) ? esrc[start + 2] : i0;      // idx of edge j+2
        ushort4 k0 = *((const ushort4*)(K + (size_t)i0 * 256) + lane);
        ushort4 v0 = *((const ushort4*)(V + (size_t)i0 * 256) + lane);
        ushort4 k1 = *((const ushort4*)(K + (size_t)i1 * 256) + lane);
        ushort4 v1 = *((const ushort4*)(V + (size_t)i1 * 256) + lane);

        for (int j = start; j < end; j++) {
            ushort4 kc = k0, vc = v0;
            k0 = k1; v0 = v1;
            if (j + 2 < end) {
                k1 = *((const ushort4*)(K + (size_t)i2 * 256) + lane);
                v1 = *((const ushort4*)(V + (size_t)i2 * 256) + lane);
            }
            i2 = (j + 3 < end) ? esrc[j + 3] : 0;

            float p = bf2f(kc.x) * q0 + bf2f(kc.y) * q1 +
                      bf2f(kc.z) * q2 + bf2f(kc.w) * q3;
            p += __shfl_xor(p, 1, 64);
            p += __shfl_xor(p, 2, 64);
            p += __shfl_xor(p, 4, 64);
            p += __shfl_xor(p, 8, 64);
            p *= 0.125f;                           // 1/sqrt(64)

            float mn = fmaxf(m, p);
            float sc = __expf(m - mn);             // first iter: exp(-huge)=0
            float w  = __expf(p - mn);
            l = l * sc + w;
            a0 = a0 * sc + w * bf2f(vc.x);
            a1 = a1 * sc + w * bf2f(vc.y);
            a2 = a2 * sc + w * bf2f(vc.z);
            a3 = a3 * sc + w * bf2f(vc.w);
            m = mn;
        }
        float inv = 1.0f / l;
        o = make_float4(a0 * inv, a1 * inv, a2 * inv, a3 * inv);
    }
    *((float4*)(out + (size_t)d * 256) + lane) = o;   // empty dst -> zeros
}

// --------------------------------------------------------------- launcher
extern "C" void kernel_launch(void* const* d_in, const int* in_sizes, int n_in,
                              void* d_out, int out_size, void* d_ws, size_t ws_size,
                              hipStream_t stream) {
    const float* h_src   = (const float*)d_in[0];
    const float* h_dst   = (const float*)d_in[1];
    const int*   src_idx = (const int*)d_in[2];
    const int*   dst_idx = (const int*)d_in[3];
    const float* Wq      = (const float*)d_in[4];
    const float* bq      = (const float*)d_in[5];
    const float* Wk      = (const float*)d_in[6];
    const float* bk      = (const float*)d_in[7];
    const float* Wv      = (const float*)d_in[8];
    const float* bv      = (const float*)d_in[9];
    float* out = (float*)d_out;

    char* ws = (char*)d_ws;
    size_t off = 0;
    auto take = [&](size_t bytes) { char* p = ws + off; off = (off + bytes + 255) & ~(size_t)255; return p; };
    unsigned short* Q       = (unsigned short*)take((size_t)N_DST * 256 * 2);
    unsigned short* K       = (unsigned short*)take((size_t)N_SRC * 256 * 2);
    unsigned short* V       = (unsigned short*)take((size_t)N_SRC * 256 * 2);
    unsigned short* Wb      = (unsigned short*)take((size_t)3 * 65536 * 2);
    int*            cnt     = (int*)take((size_t)N_DST * 4);
    int*            offsets = (int*)take((size_t)(N_DST + 1) * 4);
    int*            cursor  = (int*)take((size_t)N_DST * 4);
    int*            esrc    = (int*)take((size_t)N_EDGES * 4);
    int*            bsum    = (int*)take((size_t)64 * 4);
    (void)ws_size; (void)in_sizes; (void)n_in; (void)out_size;

    // weights cvt + cnt zeroing (folded memset): 96 + 49 blocks
    wcvt_kernel<<<WCVT_BLKS + SCAN_NBLK, 256, 0, stream>>>(Wq, Wk, Wv, Wb, cnt);

    // CSR build: hist -> scan (2 launches, fixup folded into consumers)
    hist_kernel<<<(N_EDGES + 255) / 256, 256, 0, stream>>>(dst_idx, cnt);
    scan_local_kernel<<<SCAN_NBLK, 1024, 0, stream>>>(cnt, offsets, cursor, bsum);
    scan_base_kernel<<<1, 64, 0, stream>>>(bsum);
    scatter_kernel<<<(N_EDGES + 255) / 256, 256, 0, stream>>>(src_idx, dst_idx,
                                                              cursor, bsum, esrc);

    // Q/K/V projections: restored r5 structure (128x256 tile, 512 thr)
    gemm_kernel<<<dim3((N_SRC + BM - 1) / BM, 1, 3), 512, 0, stream>>>(
        h_src, h_dst, Wb, bq, bk, bv, Q, K, V);

    agg_kernel<<<(N_DST + 3) / 4, 256, 0, stream>>>(esrc, offsets, bsum, Q, K, V, out);
}